// Round 3
// baseline (71.359 us; speedup 1.0000x reference)
//
#include <hip/hip_runtime.h>
#include <math.h>

// Problem constants
#define NB 4
#define BINS 256
#define HW (512*512)

// Pass-1 decomposition
#define CHUNKS 64                      // blocks per batch
#define PIX_PER_BLOCK (HW / CHUNKS)    // 4096
#define F4_PER_THREAD (PIX_PER_BLOCK / 4 / 256)  // 4

// ws layout: Hp[NB*CHUNKS*BINS] | Sp[NB*CHUNKS*BINS] | acc(float) | cnt(uint)

// Pass 1: per-(batch,chunk) hard histogram + first moment partials.
// Plain stores (no global atomics) -> no zero-init needed anywhere.
__global__ __launch_bounds__(256) void hist_part(const float* __restrict__ y,
                                                 float* __restrict__ Hp,
                                                 float* __restrict__ Sp,
                                                 float* __restrict__ acc) {
    __shared__ float lh[BINS];
    __shared__ float ls[BINS];
    const int t = threadIdx.x;
    lh[t] = 0.0f;
    ls[t] = 0.0f;
    if (blockIdx.x == 0 && blockIdx.y == 0 && t == 0) {
        acc[0] = 0.0f;                       // entropy accumulator
        ((unsigned*)acc)[1] = 0u;            // completion counter
    }
    __syncthreads();

    const int b = blockIdx.y;
    const float4* src = reinterpret_cast<const float4*>(
        y + (size_t)b * HW + (size_t)blockIdx.x * PIX_PER_BLOCK);

#pragma unroll
    for (int i = 0; i < F4_PER_THREAD; ++i) {
        float4 v = src[t + 256 * i];
        float vals[4] = {v.x, v.y, v.z, v.w};
#pragma unroll
        for (int c = 0; c < 4; ++c) {
            float f = vals[c];
            int bin = (int)(f * 256.0f);
            bin = bin < 0 ? 0 : (bin > 255 ? 255 : bin);
            atomicAdd(&lh[bin], 1.0f);       // LDS atomic, low contention
            atomicAdd(&ls[bin], f);
        }
    }
    __syncthreads();
    const size_t o = ((size_t)b * CHUNKS + blockIdx.x) * BINS + t;
    Hp[o] = lh[t];                           // coalesced plain store
    Sp[o] = ls[t];
}

// Pass 2 (fused): per-batch block reduces chunk partials, builds the Taylor
// kernel tables, does the 256-tap correlation, computes the per-batch entropy
// partial, and the last-finishing block writes 1/d.
// hist[b][j] = sum_m H[m]*K0[m-j] + M1[m]*K1[m-j],  M1[m] = Σ(y - c_m)
__global__ __launch_bounds__(256) void entropy_fused(const float* __restrict__ Hp,
                                                     const float* __restrict__ Sp,
                                                     float* __restrict__ acc,
                                                     float* __restrict__ out) {
    __shared__ float2 K01[512];              // entries 0..510, idx = (m-j)+255
    __shared__ float2 HM[BINS];
    __shared__ float red[4];

    const int t = threadIdx.x;
    const int b = blockIdx.x;
    const float DELTA = 1.0f / 256.0f;
    const float SIGMA = 30.0f;

    // Reduce 64 chunk partials for bin t — fully coalesced across threads.
    float H = 0.0f, S = 0.0f;
    const float* hb = Hp + (size_t)b * CHUNKS * BINS + t;
    const float* sb = Sp + (size_t)b * CHUNKS * BINS + t;
#pragma unroll 8
    for (int c = 0; c < CHUNKS; ++c) {
        H += hb[c * BINS];
        S += sb[c * BINS];
    }
    HM[t] = make_float2(H, S - H * ((float)t + 0.5f) * DELTA);

    // Kernel tables: 511 sigmoid-pair evals per block (trivial VALU).
    for (int i = t; i < 2 * BINS - 1; i += 256) {
        float x = (float)(i - (BINS - 1)) * DELTA;   // c_m - c_j
        float zp = SIGMA * (x + 0.5f * DELTA);
        float zm = SIGMA * (x - 0.5f * DELTA);
        float sp = 1.0f / (1.0f + __expf(-zp));
        float sm = 1.0f / (1.0f + __expf(-zm));
        K01[i] = make_float2(sp - sm,
                             SIGMA * (sp * (1.0f - sp) - sm * (1.0f - sm)));
    }
    __syncthreads();

    // 256-tap correlation for output bin j = t.
    const int j = t;
    float hist = 0.0f;
#pragma unroll 8
    for (int m = 0; m < BINS; ++m) {
        float2 hm = HM[m];                           // LDS broadcast
        float2 k  = K01[m - j + (BINS - 1)];         // stride-1 across lanes
        hist = fmaf(hm.x, k.x, hist);
        hist = fmaf(hm.y, k.y, hist);
    }

    float p = hist * (1.0f / (float)HW) + 1e-6f;
    float e = -p * __logf(p);

    // block-reduce the 256 entropy terms
    const int lane = t & 63, wid = t >> 6;
#pragma unroll
    for (int off = 32; off > 0; off >>= 1) e += __shfl_down(e, off);
    if (lane == 0) red[wid] = e;
    __syncthreads();

    if (t == 0) {
        float part = red[0] + red[1] + red[2] + red[3];
        atomicAdd(acc, part);                        // device-scope
        __threadfence();
        unsigned old = atomicAdd(((unsigned*)acc) + 1, 1u);
        if (old == NB - 1) {                         // last block finishes
            __threadfence();
            float d = atomicAdd(acc, 0.0f);          // coherent read of total
            out[0] = 1.0f / d;
        }
    }
}

extern "C" void kernel_launch(void* const* d_in, const int* in_sizes, int n_in,
                              void* d_out, int out_size, void* d_ws, size_t ws_size,
                              hipStream_t stream) {
    const float* y = (const float*)d_in[0];
    float* Hp = (float*)d_ws;
    float* Sp = Hp + NB * CHUNKS * BINS;
    float* acc = Sp + NB * CHUNKS * BINS;

    hist_part<<<dim3(CHUNKS, NB), 256, 0, stream>>>(y, Hp, Sp, acc);
    entropy_fused<<<NB, 256, 0, stream>>>(Hp, Sp, acc, (float*)d_out);
}

// Round 5
// 61.130 us; speedup vs baseline: 1.1673x; 1.1673x over previous
//
#include <hip/hip_runtime.h>
#include <math.h>

// Problem constants
#define NB 4
#define BINS 256
#define HW (512*512)

// Pass-1 decomposition
#define CHUNKS 64                      // blocks per batch (256 blocks total = 1/CU)
#define PIX_PER_BLOCK (HW / CHUNKS)    // 4096
#define F4_PER_THREAD (PIX_PER_BLOCK / 4 / 256)  // 4

// ws layout: Hp[NB*CHUNKS*BINS] uint partial counts | acc(float) + cnt(uint)
//
// Numerics note: with SIGMA*DELTA = 0.117 the soft-bin kernel k(x) is ~50 bins
// wide (peak 0.029) and near-linear over one bin, so the 0th-order expansion
// hist[j] = sum_m H[m]*K0[m-j] (hard histogram convolved with the kernel
// table) is accurate to ~1e-4 relative per hist bin -> ~1e-6 on the output,
// vs a 2e-2 relative tolerance. The first-moment term (round 3) is dropped.

// Pass 1: per-(batch,chunk) hard histogram partials. One LDS atomic per pixel.
__global__ __launch_bounds__(256) void hist_part(const float* __restrict__ y,
                                                 unsigned* __restrict__ Hp,
                                                 float* __restrict__ acc) {
    __shared__ unsigned lh[BINS];
    const int t = threadIdx.x;
    lh[t] = 0u;
    if (blockIdx.x == 0 && blockIdx.y == 0 && t == 0) {
        acc[0] = 0.0f;                       // entropy accumulator
        ((unsigned*)acc)[1] = 0u;            // completion counter
    }
    __syncthreads();

    const int b = blockIdx.y;
    const float4* src = reinterpret_cast<const float4*>(
        y + (size_t)b * HW + (size_t)blockIdx.x * PIX_PER_BLOCK);

#pragma unroll
    for (int i = 0; i < F4_PER_THREAD; ++i) {
        float4 v = src[t + 256 * i];
        float vals[4] = {v.x, v.y, v.z, v.w};
#pragma unroll
        for (int c = 0; c < 4; ++c) {
            int bin = (int)(vals[c] * 256.0f);
            bin = bin < 0 ? 0 : (bin > 255 ? 255 : bin);
            atomicAdd(&lh[bin], 1u);         // ds_add_u32, ~2-4-way contention
        }
    }
    __syncthreads();
    Hp[((size_t)b * CHUNKS + blockIdx.x) * BINS + t] = lh[t];  // coalesced
}

// Pass 2 (fused, 4 blocks = 1/batch): reduce chunk partials, build the 511-tap
// kernel table (511 sigmoid pairs per block), 256-tap correlation, entropy
// partial, last-finishing block writes 1/d.
__global__ __launch_bounds__(256) void entropy_fused(const unsigned* __restrict__ Hp,
                                                     float* __restrict__ acc,
                                                     float* __restrict__ out) {
    __shared__ float K0[512];                // entries 0..510, idx = (m-j)+255
    __shared__ float Hs[BINS];
    __shared__ float red[4];

    const int t = threadIdx.x;
    const int b = blockIdx.x;
    const float DELTA = 1.0f / 256.0f;
    const float SIGMA = 30.0f;

    // Reduce 64 chunk partials for bin t — fully coalesced (64 KB from L2).
    unsigned H = 0u;
    const unsigned* hb = Hp + (size_t)b * CHUNKS * BINS + t;
#pragma unroll 8
    for (int c = 0; c < CHUNKS; ++c) H += hb[c * BINS];
    Hs[t] = (float)H;

    // Kernel table.
    for (int i = t; i < 2 * BINS - 1; i += 256) {
        float x = (float)(i - (BINS - 1)) * DELTA;   // c_m - c_j
        float sp = 1.0f / (1.0f + __expf(-SIGMA * (x + 0.5f * DELTA)));
        float sm = 1.0f / (1.0f + __expf(-SIGMA * (x - 0.5f * DELTA)));
        K0[i] = sp - sm;
    }
    __syncthreads();

    // 256-tap correlation for output bin j = t.
    const int j = t;
    float hist = 0.0f;
#pragma unroll 8
    for (int m = 0; m < BINS; ++m) {
        hist = fmaf(Hs[m], K0[m - j + (BINS - 1)], hist);  // broadcast + stride-1
    }

    float p = hist * (1.0f / (float)HW) + 1e-6f;
    float e = -p * __logf(p);

    // block-reduce 256 entropy terms
    const int lane = t & 63, wid = t >> 6;
#pragma unroll
    for (int off = 32; off > 0; off >>= 1) e += __shfl_down(e, off);
    if (lane == 0) red[wid] = e;
    __syncthreads();

    if (t == 0) {
        float part = red[0] + red[1] + red[2] + red[3];
        atomicAdd(acc, part);                        // device-scope
        __threadfence();
        unsigned old = atomicAdd(((unsigned*)acc) + 1, 1u);
        if (old == NB - 1) {                         // last block finishes
            __threadfence();
            float d = atomicAdd(acc, 0.0f);          // coherent read of total
            out[0] = 1.0f / d;
        }
    }
}

extern "C" void kernel_launch(void* const* d_in, const int* in_sizes, int n_in,
                              void* d_out, int out_size, void* d_ws, size_t ws_size,
                              hipStream_t stream) {
    const float* y = (const float*)d_in[0];
    unsigned* Hp = (unsigned*)d_ws;
    float* acc = (float*)(Hp + NB * CHUNKS * BINS);

    hist_part<<<dim3(CHUNKS, NB), 256, 0, stream>>>(y, Hp, acc);
    entropy_fused<<<NB, 256, 0, stream>>>(Hp, acc, (float*)d_out);
}